// Round 1
// baseline (10572.472 us; speedup 1.0000x reference)
//
#include <hip/hip_runtime.h>
#include <math.h>

#define B_   32
#define S_   1024
#define DIN  512
#define DH   512
#define KTOT 1024          // DH (H part) + DIN (x part)
#define NWG  64
#define TPB  256
#define APAD 1032          // A row stride in elems (1024 + 8 pad -> 2-way LDS banking)

typedef short short8 __attribute__((ext_vector_type(8)));  // 8 bf16 (4 VGPRs)
typedef float f32x4  __attribute__((ext_vector_type(4)));

__device__ __forceinline__ unsigned short f2bf(float f) {
  unsigned u = __float_as_uint(f);
  u += 0x7FFFu + ((u >> 16) & 1u);   // RNE
  return (unsigned short)(u >> 16);
}

// sense-reversing grid barrier; bar[0]=count, bar[1]=generation
__device__ __forceinline__ void grid_barrier(unsigned* bar) {
  __syncthreads();
  if (threadIdx.x == 0) {
    __threadfence();  // agent-scope release of hbuf/out writes (wbl2 on gfx950)
    unsigned g = __hip_atomic_load(&bar[1], __ATOMIC_RELAXED, __HIP_MEMORY_SCOPE_AGENT);
    unsigned a = __hip_atomic_fetch_add(&bar[0], 1u, __ATOMIC_ACQ_REL, __HIP_MEMORY_SCOPE_AGENT);
    if (a == (unsigned)(NWG - 1)) {
      __hip_atomic_store(&bar[0], 0u, __ATOMIC_RELAXED, __HIP_MEMORY_SCOPE_AGENT);
      __hip_atomic_store(&bar[1], g + 1u, __ATOMIC_RELEASE, __HIP_MEMORY_SCOPE_AGENT);
    } else {
      while (__hip_atomic_load(&bar[1], __ATOMIC_ACQUIRE, __HIP_MEMORY_SCOPE_AGENT) == g) {
        __builtin_amdgcn_s_sleep(1);
      }
    }
    __threadfence();  // acquire side: invalidate stale L1/L2 before next step's reads
  }
  __syncthreads();
}

// Rearrange [Wh;Wx] (fp32, per gate) into per-WG B-operand layout, bf16:
// Bws[w][c(0..31)][k(0..1023)], c = gate*8 + j, hcol = 8w + j, k<512 -> Wh, else Wx.
__global__ void k_prep(const float* __restrict__ Whi, const float* __restrict__ Whf,
                       const float* __restrict__ Who, const float* __restrict__ Whc,
                       const float* __restrict__ Wxi, const float* __restrict__ Wxf,
                       const float* __restrict__ Wxo, const float* __restrict__ Wxc,
                       unsigned short* __restrict__ Bws, unsigned* __restrict__ bar) {
  int chunk = blockIdx.x * TPB + threadIdx.x;      // 0..262143, 8 elems each
  int w   = chunk >> 12;
  int rem = chunk & 4095;
  int c   = rem >> 7;
  int k8  = (rem & 127) << 3;
  int g    = c >> 3;
  int hcol = (w << 3) | (c & 7);
  const float* Wh = (g == 0) ? Whi : (g == 1) ? Whf : (g == 2) ? Who : Whc;
  const float* Wx = (g == 0) ? Wxi : (g == 1) ? Wxf : (g == 2) ? Wxo : Wxc;
  short8 sv;
  for (int j = 0; j < 8; ++j) {
    int k = k8 + j;
    float f = (k < DH) ? Wh[(size_t)k * DH + hcol] : Wx[(size_t)(k - DH) * DH + hcol];
    sv[j] = (short)f2bf(f);
  }
  *(short8*)(Bws + (size_t)chunk * 8) = sv;
  if (blockIdx.x == 0 && threadIdx.x < 2) bar[threadIdx.x] = 0;  // reset barrier each call
}

// Persistent fused LSTM scan: 64 WGs, WG w owns hcols [8w, 8w+8) for all 4 gates,
// all 32 batches. Per step: [32 x 1024] @ [1024 x 32] via MFMA (split-K over 4 waves,
// B resident in registers), LDS reduce, elementwise gate update, 1 grid barrier.
__launch_bounds__(TPB, 1)
__global__ void k_scan(const float* __restrict__ x,
                       const float* __restrict__ bi, const float* __restrict__ bfv,
                       const float* __restrict__ bo, const float* __restrict__ bc,
                       const unsigned short* __restrict__ Bws,
                       unsigned short* __restrict__ hbuf,   // 2 buffers of [32][512] bf16
                       unsigned* __restrict__ bar,
                       float* __restrict__ out) {
  __shared__ unsigned short As[B_ * APAD];   // 66,048 B: A = [H | x_t] bf16, padded
  __shared__ float R[4 * 64 * 16];           // 16 KB: per-wave partial accumulators
  __shared__ float Cst[TPB];                 // cell state, thread-private slot

  const int tid  = threadIdx.x;
  const int w    = blockIdx.x;
  const int lane = tid & 63;
  const int wv   = tid >> 6;                 // wave 0..3 = K-slice owner

  const int eb   = tid >> 3;                 // elementwise: batch 0..31
  const int ej   = tid & 7;                  // elementwise: local hcol 0..7
  const int hcol = (w << 3) | ej;

  const float pbi = bi[hcol], pbf = bfv[hcol], pbo = bo[hcol], pbc = bc[hcol];

  Cst[tid] = 0.0f;
  hbuf[eb * DH + hcol] = 0;                  // zero H0 (buffer 0)

  // Load this wave's B fragments into registers: kslice = [wv*256, wv*256+256)
  short8 bfrag[8][2];
  {
    const int col0 = lane & 15;
    const int kq   = (lane >> 4) * 8;
    for (int ks = 0; ks < 8; ++ks) {
      int kb = wv * 256 + ks * 32 + kq;
      for (int ni = 0; ni < 2; ++ni) {
        int col = ni * 16 + col0;
        bfrag[ks][ni] = *(const short8*)(Bws + ((size_t)(w * 32 + col) * KTOT + kb));
      }
    }
  }

  grid_barrier(bar);                          // H0 visible everywhere

  for (int t = 0; t < S_; ++t) {
    const unsigned short* hr = hbuf + (t & 1) * (B_ * DH);
    unsigned short*       hw = hbuf + ((t + 1) & 1) * (B_ * DH);

    // stage H (32 KB bf16) -> As[:, 0:512]
    for (int i = 0; i < 8; ++i) {
      int flat = tid + i * TPB;              // 0..2047 chunks of 16B
      int row = flat >> 6, cc = flat & 63;
      uint4 v = *(const uint4*)(hr + row * DH + cc * 8);
      *(uint4*)(&As[row * APAD + cc * 8]) = v;
    }
    // stage x_t (64 KB fp32 -> bf16) -> As[:, 512:1024]
    for (int i = 0; i < 16; ++i) {
      int flat = tid + i * TPB;              // 0..4095 chunks of 4 floats
      int row = flat >> 7, cc = flat & 127;
      float4 v = *(const float4*)(x + (size_t)row * (S_ * DIN) + (size_t)t * DIN + cc * 4);
      uint2 p;
      p.x = (unsigned)f2bf(v.x) | ((unsigned)f2bf(v.y) << 16);
      p.y = (unsigned)f2bf(v.z) | ((unsigned)f2bf(v.w) << 16);
      *(uint2*)(&As[row * APAD + DIN + cc * 4]) = p;
    }
    __syncthreads();

    // split-K MFMA: wave wv does k in [wv*256, wv*256+256), full 32x32 tile
    f32x4 acc00 = {0,0,0,0}, acc01 = {0,0,0,0}, acc10 = {0,0,0,0}, acc11 = {0,0,0,0};
    {
      const int r0 = lane & 15;
      const int kq = (lane >> 4) * 8;
      for (int ks = 0; ks < 8; ++ks) {
        int koff = wv * 256 + ks * 32 + kq;
        short8 a0 = *(const short8*)(&As[r0 * APAD + koff]);
        short8 a1 = *(const short8*)(&As[(r0 + 16) * APAD + koff]);
        acc00 = __builtin_amdgcn_mfma_f32_16x16x32_bf16(a0, bfrag[ks][0], acc00, 0, 0, 0);
        acc01 = __builtin_amdgcn_mfma_f32_16x16x32_bf16(a0, bfrag[ks][1], acc01, 0, 0, 0);
        acc10 = __builtin_amdgcn_mfma_f32_16x16x32_bf16(a1, bfrag[ks][0], acc10, 0, 0, 0);
        acc11 = __builtin_amdgcn_mfma_f32_16x16x32_bf16(a1, bfrag[ks][1], acc11, 0, 0, 0);
      }
    }
    // dump partials for cross-wave reduction
    {
      float* rp = &R[(wv * 64 + lane) * 16];
      *(f32x4*)(rp + 0)  = acc00;
      *(f32x4*)(rp + 4)  = acc01;
      *(f32x4*)(rp + 8)  = acc10;
      *(f32x4*)(rp + 12) = acc11;
    }
    __syncthreads();

    // elementwise: thread (eb, ej) gathers 4 gate pre-activations
    float pre[4];
    {
      int r = eb & 15, mi = eb >> 4, reg = eb & 3;
      int lq = (r >> 2) * 16;
      for (int g = 0; g < 4; ++g) {
        int c  = g * 8 + ej;
        int ni = c >> 4;
        int ln = (c & 15) + lq;
        int idx = (mi * 2 + ni) * 4 + reg;
        float s = 0.f;
        for (int v = 0; v < 4; ++v) s += R[(v * 64 + ln) * 16 + idx];
        pre[g] = s;
      }
    }
    float I  = 1.f / (1.f + expf(-(pre[0] + pbi)));
    float F  = 1.f / (1.f + expf(-(pre[1] + pbf)));
    float O  = 1.f / (1.f + expf(-(pre[2] + pbo)));
    float Cc = tanhf(pre[3] + pbc);
    float Cn = F * Cst[tid] + I * Cc;
    Cst[tid] = Cn;
    float H = O * tanhf(Cn);

    out[(size_t)eb * (S_ * DH) + (size_t)t * DH + hcol] = H;
    hw[eb * DH + hcol] = f2bf(H);
    if (t == S_ - 1) out[(size_t)(B_ * S_ * DH) + eb * DH + hcol] = H;  // Hf

    grid_barrier(bar);
  }
}

extern "C" void kernel_launch(void* const* d_in, const int* in_sizes, int n_in,
                              void* d_out, int out_size, void* d_ws, size_t ws_size,
                              hipStream_t stream) {
  const float* x   = (const float*)d_in[0];
  const float* Wxi = (const float*)d_in[1];
  const float* Whi = (const float*)d_in[2];
  const float* bi  = (const float*)d_in[3];
  const float* Wxf = (const float*)d_in[4];
  const float* Whf = (const float*)d_in[5];
  const float* bfv = (const float*)d_in[6];
  const float* Wxo = (const float*)d_in[7];
  const float* Who = (const float*)d_in[8];
  const float* bo  = (const float*)d_in[9];
  const float* Wxc = (const float*)d_in[10];
  const float* Whc = (const float*)d_in[11];
  const float* bc  = (const float*)d_in[12];
  float* out = (float*)d_out;

  // ws layout: Bws 4 MB | hbuf 64 KB | barrier 8 B  (total ~4.26 MB)
  unsigned short* Bws  = (unsigned short*)d_ws;
  unsigned short* hbuf = (unsigned short*)((char*)d_ws + (size_t)4 * 1024 * 1024 + 65536);
  unsigned*       bar  = (unsigned*)((char*)d_ws + (size_t)4 * 1024 * 1024 + 65536 + 2 * B_ * DH * 2);

  k_prep<<<1024, TPB, 0, stream>>>(Whi, Whf, Who, Whc, Wxi, Wxf, Wxo, Wxc, Bws, bar);
  k_scan<<<NWG, TPB, 0, stream>>>(x, bi, bfv, bo, bc, Bws, hbuf, bar, out);
}

// Round 2
// 4677.397 us; speedup vs baseline: 2.2603x; 2.2603x over previous
//
#include <hip/hip_runtime.h>
#include <math.h>

#define B_   32
#define S_   1024
#define DIN  512
#define DH   512
#define KTOT 1024          // DH (H part) + DIN (x part)
#define NWG  64
#define TPB  256
#define APAD 1032          // A row stride in elems (1024 + 8 pad)

typedef short short8 __attribute__((ext_vector_type(8)));  // 8 bf16 (4 VGPRs)
typedef float f32x4  __attribute__((ext_vector_type(4)));
typedef unsigned long long u64;

__device__ __forceinline__ unsigned short f2bf(float f) {
  unsigned u = __float_as_uint(f);
  u += 0x7FFFu + ((u >> 16) & 1u);   // RNE
  return (unsigned short)(u >> 16);
}

__device__ __forceinline__ float sigmoid_f(float z) {
  return 1.f / (1.f + __expf(-z));
}
__device__ __forceinline__ float tanh_f(float z) {
  float e = __expf(-2.f * fabsf(z));
  float t = (1.f - e) / (1.f + e);
  return z < 0.f ? -t : t;
}

__device__ __forceinline__ f32x4 mfma16(short8 a, short8 b, f32x4 c) {
  return __builtin_amdgcn_mfma_f32_16x16x32_bf16(a, b, c, 0, 0, 0);
}

// Rearrange [Wh;Wx] (fp32, per gate) into per-WG B-operand layout, bf16:
// Bws[w][c(0..31)][k(0..1023)], c = gate*8 + j, hcol = 8w + j, k<512 -> Wh, else Wx.
__global__ void k_prep(const float* __restrict__ Whi, const float* __restrict__ Whf,
                       const float* __restrict__ Who, const float* __restrict__ Whc,
                       const float* __restrict__ Wxi, const float* __restrict__ Wxf,
                       const float* __restrict__ Wxo, const float* __restrict__ Wxc,
                       unsigned short* __restrict__ Bws, unsigned* __restrict__ bar) {
  int chunk = blockIdx.x * TPB + threadIdx.x;      // 0..262143, 8 elems each
  int w   = chunk >> 12;
  int rem = chunk & 4095;
  int c   = rem >> 7;
  int k8  = (rem & 127) << 3;
  int g    = c >> 3;
  int hcol = (w << 3) | (c & 7);
  const float* Wh = (g == 0) ? Whi : (g == 1) ? Whf : (g == 2) ? Who : Whc;
  const float* Wx = (g == 0) ? Wxi : (g == 1) ? Wxf : (g == 2) ? Wxo : Wxc;
  short8 sv;
  for (int j = 0; j < 8; ++j) {
    int k = k8 + j;
    float f = (k < DH) ? Wh[(size_t)k * DH + hcol] : Wx[(size_t)(k - DH) * DH + hcol];
    sv[j] = (short)f2bf(f);
  }
  *(short8*)(Bws + (size_t)chunk * 8) = sv;
  if (blockIdx.x == 0 && threadIdx.x < 256) bar[threadIdx.x] = 0;  // reset barrier counters
}

// Persistent fused LSTM scan. Cross-WG coherence entirely via sc0/sc1 (agent-scope
// relaxed atomic) accesses to hbuf + barrier counters -> NO buffer_wbl2/buffer_inv,
// L2 stays warm for x. One monotonic 8-counter barrier per step; x staging and the
// x-half of the MFMA overlap the inter-WG wait.
__launch_bounds__(TPB, 1)
__global__ void k_scan(const float* __restrict__ x,
                       const float* __restrict__ bi, const float* __restrict__ bfv,
                       const float* __restrict__ bo, const float* __restrict__ bc,
                       const unsigned short* __restrict__ Bws,
                       u64* __restrict__ hbuf64,   // 2 buffers of [32][512] bf16 = 2x4096 u64
                       unsigned* __restrict__ bar, // 8 counters, 128B apart
                       float* __restrict__ out) {
  __shared__ unsigned short As[B_ * APAD];   // A = [H | x_t] bf16, padded
  __shared__ float R[4 * 64 * 16];           // per-wave partial accumulators
  __shared__ unsigned short Hs[TPB];         // bf16 H staging for packed publish

  const int tid  = threadIdx.x;
  const int w    = blockIdx.x;
  const int lane = tid & 63;
  const int wv   = tid >> 6;                 // wave 0..3 = K-slice owner

  const int eb   = tid >> 3;                 // elementwise: batch 0..31
  const int ej   = tid & 7;                  // elementwise: local hcol 0..7
  const int hcol = (w << 3) | ej;

  const float pbi = bi[hcol], pbf = bfv[hcol], pbo = bo[hcol], pbc = bc[hcol];
  float Creg = 0.f;

  // wave 0: zero H0 (buffer 0) with coherent stores (redundant across WGs, benign)
  if (wv == 0) {
    #pragma unroll
    for (int i = 0; i < 64; ++i)
      __hip_atomic_store(&hbuf64[lane + i * 64], 0ULL,
                         __ATOMIC_RELAXED, __HIP_MEMORY_SCOPE_AGENT);
  }

  // B fragments -> registers (weights resident for the whole scan)
  short8 bfrag[8][2];
  {
    const int col0 = lane & 15;
    const int kqb  = (lane >> 4) * 8;
    #pragma unroll
    for (int ks = 0; ks < 8; ++ks) {
      int kb = (ks < 4) ? (wv * 128 + ks * 32 + kqb)
                        : (DH + wv * 128 + (ks - 4) * 32 + kqb);
      #pragma unroll
      for (int ni = 0; ni < 2; ++ni) {
        int col = ni * 16 + col0;
        bfrag[ks][ni] = *(const short8*)(Bws + ((size_t)(w * 32 + col) * KTOT + kb));
      }
    }
  }

  // stage x_0 -> As[:, 512:1024)
  #pragma unroll
  for (int i = 0; i < 16; ++i) {
    int flat = tid + i * TPB;
    int row = flat >> 7, cc = flat & 127;
    float4 v = *(const float4*)(x + (size_t)row * (S_ * DIN) + cc * 4);
    uint2 p;
    p.x = (unsigned)f2bf(v.x) | ((unsigned)f2bf(v.y) << 16);
    p.y = (unsigned)f2bf(v.z) | ((unsigned)f2bf(v.w) << 16);
    *(uint2*)(&As[row * APAD + DIN + cc * 4]) = p;
  }

  // arm phase 1 (H0 zeros are wave-0 stores; tid0's vmcnt(0) covers them)
  if (tid == 0) {
    __builtin_amdgcn_s_waitcnt(0);
    __hip_atomic_fetch_add(&bar[(w & 7) * 32], 1u,
                           __ATOMIC_RELAXED, __HIP_MEMORY_SCOPE_AGENT);
  }
  __syncthreads();

  const int r0 = lane & 15;
  const int kq = (lane >> 4) * 8;

  // x-part MFMA for t=0
  f32x4 acc00 = {0,0,0,0}, acc01 = {0,0,0,0}, acc10 = {0,0,0,0}, acc11 = {0,0,0,0};
  #pragma unroll
  for (int ks = 4; ks < 8; ++ks) {
    int koff = DH + wv * 128 + (ks - 4) * 32 + kq;
    short8 a0 = *(const short8*)(&As[r0 * APAD + koff]);
    short8 a1 = *(const short8*)(&As[(r0 + 16) * APAD + koff]);
    acc00 = mfma16(a0, bfrag[ks][0], acc00);
    acc01 = mfma16(a0, bfrag[ks][1], acc01);
    acc10 = mfma16(a1, bfrag[ks][0], acc10);
    acc11 = mfma16(a1, bfrag[ks][1], acc11);
  }

  for (int t = 0; t < S_; ++t) {
    // ---- wait: sum of 8 counters >= 64*(t+1) ----
    if (tid == 0) {
      const unsigned target = (unsigned)(NWG * (t + 1));
      for (;;) {
        unsigned c[8];
        #pragma unroll
        for (int i = 0; i < 8; ++i)
          c[i] = __hip_atomic_load(&bar[i * 32], __ATOMIC_RELAXED, __HIP_MEMORY_SCOPE_AGENT);
        unsigned s = 0;
        #pragma unroll
        for (int i = 0; i < 8; ++i) s += c[i];
        if (s >= target) break;
        __builtin_amdgcn_s_sleep(1);
      }
    }
    __syncthreads();

    // ---- stage H_{t-1} (coherent loads, batched for overlapped latency) ----
    {
      u64* hr = hbuf64 + (size_t)(t & 1) * 4096;
      u64 tmp[16];
      #pragma unroll
      for (int i = 0; i < 16; ++i)
        tmp[i] = __hip_atomic_load(&hr[tid + i * TPB],
                                   __ATOMIC_RELAXED, __HIP_MEMORY_SCOPE_AGENT);
      #pragma unroll
      for (int i = 0; i < 16; ++i) {
        int flat = tid + i * TPB;
        int row = flat >> 7, cc = flat & 127;
        *(u64*)(&As[row * APAD + cc * 4]) = tmp[i];
      }
    }
    __syncthreads();

    // ---- H-part MFMA (accumulate onto x-part already in accs) ----
    #pragma unroll
    for (int ks = 0; ks < 4; ++ks) {
      int koff = wv * 128 + ks * 32 + kq;
      short8 a0 = *(const short8*)(&As[r0 * APAD + koff]);
      short8 a1 = *(const short8*)(&As[(r0 + 16) * APAD + koff]);
      acc00 = mfma16(a0, bfrag[ks][0], acc00);
      acc01 = mfma16(a0, bfrag[ks][1], acc01);
      acc10 = mfma16(a1, bfrag[ks][0], acc10);
      acc11 = mfma16(a1, bfrag[ks][1], acc11);
    }

    {
      float* rp = &R[(wv * 64 + lane) * 16];
      *(f32x4*)(rp + 0)  = acc00;
      *(f32x4*)(rp + 4)  = acc01;
      *(f32x4*)(rp + 8)  = acc10;
      *(f32x4*)(rp + 12) = acc11;
    }
    __syncthreads();

    // ---- elementwise gate math ----
    float pre[4];
    {
      int r = eb & 15, mi = eb >> 4, reg = eb & 3;
      int lq = (r >> 2) * 16;
      #pragma unroll
      for (int g = 0; g < 4; ++g) {
        int c  = g * 8 + ej;
        int ni = c >> 4;
        int ln = (c & 15) + lq;
        int idx = (mi * 2 + ni) * 4 + reg;
        float s = 0.f;
        #pragma unroll
        for (int v = 0; v < 4; ++v) s += R[(v * 64 + ln) * 16 + idx];
        pre[g] = s;
      }
    }
    float I  = sigmoid_f(pre[0] + pbi);
    float F  = sigmoid_f(pre[1] + pbf);
    float O  = sigmoid_f(pre[2] + pbo);
    float Cc = tanh_f(pre[3] + pbc);
    Creg = F * Creg + I * Cc;
    float H = O * tanh_f(Creg);

    out[(size_t)eb * (S_ * DH) + (size_t)t * DH + hcol] = H;
    if (t == S_ - 1) out[(size_t)(B_ * S_ * DH) + eb * DH + hcol] = H;  // Hf
    Hs[tid] = f2bf(H);
    __syncthreads();

    if (t + 1 < S_) {
      // ---- publish H_t (wave 0, packed 8B coherent stores) + arm ----
      if (tid < 64) {
        u64 v = (u64)Hs[tid * 4]
              | ((u64)Hs[tid * 4 + 1] << 16)
              | ((u64)Hs[tid * 4 + 2] << 32)
              | ((u64)Hs[tid * 4 + 3] << 48);
        int ebp = tid >> 1, halfp = tid & 1;
        u64* hw = hbuf64 + (size_t)((t + 1) & 1) * 4096;
        __hip_atomic_store(&hw[ebp * 128 + 2 * w + halfp], v,
                           __ATOMIC_RELAXED, __HIP_MEMORY_SCOPE_AGENT);
      }
      if (tid == 0) {
        __builtin_amdgcn_s_waitcnt(0);   // drain wave-0 publish stores to LLC
        __hip_atomic_fetch_add(&bar[(w & 7) * 32], 1u,
                               __ATOMIC_RELAXED, __HIP_MEMORY_SCOPE_AGENT);
      }

      // ---- prefetch x_{t+1} + x-part MFMA (overlaps other WGs' latency) ----
      acc00 = (f32x4){0,0,0,0}; acc01 = (f32x4){0,0,0,0};
      acc10 = (f32x4){0,0,0,0}; acc11 = (f32x4){0,0,0,0};
      #pragma unroll
      for (int i = 0; i < 16; ++i) {
        int flat = tid + i * TPB;
        int row = flat >> 7, cc = flat & 127;
        float4 v = *(const float4*)(x + (size_t)row * (S_ * DIN) + (size_t)(t + 1) * DIN + cc * 4);
        uint2 p;
        p.x = (unsigned)f2bf(v.x) | ((unsigned)f2bf(v.y) << 16);
        p.y = (unsigned)f2bf(v.z) | ((unsigned)f2bf(v.w) << 16);
        *(uint2*)(&As[row * APAD + DIN + cc * 4]) = p;
      }
      __syncthreads();
      #pragma unroll
      for (int ks = 4; ks < 8; ++ks) {
        int koff = DH + wv * 128 + (ks - 4) * 32 + kq;
        short8 a0 = *(const short8*)(&As[r0 * APAD + koff]);
        short8 a1 = *(const short8*)(&As[(r0 + 16) * APAD + koff]);
        acc00 = mfma16(a0, bfrag[ks][0], acc00);
        acc01 = mfma16(a0, bfrag[ks][1], acc01);
        acc10 = mfma16(a1, bfrag[ks][0], acc10);
        acc11 = mfma16(a1, bfrag[ks][1], acc11);
      }
    }
  }
}

extern "C" void kernel_launch(void* const* d_in, const int* in_sizes, int n_in,
                              void* d_out, int out_size, void* d_ws, size_t ws_size,
                              hipStream_t stream) {
  const float* x   = (const float*)d_in[0];
  const float* Wxi = (const float*)d_in[1];
  const float* Whi = (const float*)d_in[2];
  const float* bi  = (const float*)d_in[3];
  const float* Wxf = (const float*)d_in[4];
  const float* Whf = (const float*)d_in[5];
  const float* bfv = (const float*)d_in[6];
  const float* Wxo = (const float*)d_in[7];
  const float* Who = (const float*)d_in[8];
  const float* bo  = (const float*)d_in[9];
  const float* Wxc = (const float*)d_in[10];
  const float* Whc = (const float*)d_in[11];
  const float* bc  = (const float*)d_in[12];
  float* out = (float*)d_out;

  // ws layout: Bws 4 MiB | (64 KiB gap) | hbuf 64 KiB | bar 1 KiB
  unsigned short* Bws  = (unsigned short*)d_ws;
  u64*            hbuf = (u64*)((char*)d_ws + (size_t)4 * 1024 * 1024 + 65536);
  unsigned*       bar  = (unsigned*)((char*)d_ws + (size_t)4 * 1024 * 1024 + 2 * 65536);

  k_prep<<<1024, TPB, 0, stream>>>(Whi, Whf, Who, Whc, Wxi, Wxf, Wxo, Wxc, Bws, bar);
  k_scan<<<NWG, TPB, 0, stream>>>(x, bi, bfv, bo, bc, Bws, hbuf, bar, out);
}

// Round 3
// 4377.192 us; speedup vs baseline: 2.4154x; 1.0686x over previous
//
#include <hip/hip_runtime.h>
#include <math.h>

#define B_   32
#define S_   1024
#define DIN  512
#define DH   512
#define KTOT 1024          // DH (H part) + DIN (x part)
#define NWG  64
#define TPB  256
#define APAD 1032          // A row stride in elems (1024 + 8 pad)
#define HB64 4096          // u64 per H buffer (32 batches x 128 u64)

typedef short short8 __attribute__((ext_vector_type(8)));  // 8 bf16 (4 VGPRs)
typedef float f32x4  __attribute__((ext_vector_type(4)));
typedef unsigned long long u64;

#define SENT 0xFFFFFFFFFFFFFFFFULL   // 4x bf16 NaN; |H|<1 so never produced by f2bf

__device__ __forceinline__ unsigned short f2bf(float f) {
  unsigned u = __float_as_uint(f);
  u += 0x7FFFu + ((u >> 16) & 1u);   // RNE
  return (unsigned short)(u >> 16);
}

__device__ __forceinline__ float sigmoid_f(float z) {
  return 1.f / (1.f + __expf(-z));
}
__device__ __forceinline__ float tanh_f(float z) {
  float e = __expf(-2.f * fabsf(z));
  float t = (1.f - e) / (1.f + e);
  return z < 0.f ? -t : t;
}

__device__ __forceinline__ f32x4 mfma16(short8 a, short8 b, f32x4 c) {
  return __builtin_amdgcn_mfma_f32_16x16x32_bf16(a, b, c, 0, 0, 0);
}

__device__ __forceinline__ u64 cload(const u64* p) {
  return __hip_atomic_load(p, __ATOMIC_RELAXED, __HIP_MEMORY_SCOPE_AGENT);
}
__device__ __forceinline__ void cstore(u64* p, u64 v) {
  __hip_atomic_store(p, v, __ATOMIC_RELAXED, __HIP_MEMORY_SCOPE_AGENT);
}

// Rearrange [Wh;Wx] (fp32, per gate) into per-WG B-operand layout, bf16:
// Bws[w][c(0..31)][k(0..1023)], c = gate*8 + j, hcol = 8w + j, k<512 -> Wh, else Wx.
__global__ void k_prep(const float* __restrict__ Whi, const float* __restrict__ Whf,
                       const float* __restrict__ Who, const float* __restrict__ Whc,
                       const float* __restrict__ Wxi, const float* __restrict__ Wxf,
                       const float* __restrict__ Wxo, const float* __restrict__ Wxc,
                       unsigned short* __restrict__ Bws, unsigned* __restrict__ bar) {
  int chunk = blockIdx.x * TPB + threadIdx.x;      // 0..262143, 8 elems each
  int w   = chunk >> 12;
  int rem = chunk & 4095;
  int c   = rem >> 7;
  int k8  = (rem & 127) << 3;
  int g    = c >> 3;
  int hcol = (w << 3) | (c & 7);
  const float* Wh = (g == 0) ? Whi : (g == 1) ? Whf : (g == 2) ? Who : Whc;
  const float* Wx = (g == 0) ? Wxi : (g == 1) ? Wxf : (g == 2) ? Wxo : Wxc;
  short8 sv;
  for (int j = 0; j < 8; ++j) {
    int k = k8 + j;
    float f = (k < DH) ? Wh[(size_t)k * DH + hcol] : Wx[(size_t)(k - DH) * DH + hcol];
    sv[j] = (short)f2bf(f);
  }
  *(short8*)(Bws + (size_t)chunk * 8) = sv;
  if (blockIdx.x == 0 && threadIdx.x < 256) bar[threadIdx.x] = 0;  // reset startup barrier
}

// Persistent fused LSTM scan. Inter-WG H exchange via sentinel-polled coherent
// (sc0/sc1) 8B loads on 3 rotating LLC buffers: readiness detection and data
// transfer share one round-trip; no flags, no fences, no atomics after startup.
__launch_bounds__(TPB, 1)
__global__ void k_scan(const float* __restrict__ x,
                       const float* __restrict__ bi, const float* __restrict__ bfv,
                       const float* __restrict__ bo, const float* __restrict__ bc,
                       const unsigned short* __restrict__ Bws,
                       u64* __restrict__ hbuf64,   // 3 buffers of [32][128] u64
                       unsigned* __restrict__ bar, // 8 startup counters, 128B apart
                       float* __restrict__ out) {
  __shared__ unsigned short As[B_ * APAD];   // A = [H | x_t] bf16, padded
  __shared__ float R[4 * 64 * 16];           // per-wave partial accumulators
  __shared__ unsigned short Hs[TPB];         // bf16 H staging for packed publish

  const int tid  = threadIdx.x;
  const int w    = blockIdx.x;
  const int lane = tid & 63;
  const int wv   = tid >> 6;                 // wave 0..3 = K-slice owner

  const int eb   = tid >> 3;                 // elementwise: batch 0..31
  const int ej   = tid & 7;                  // elementwise: local hcol 0..7
  const int hcol = (w << 3) | ej;

  const float pbi = bi[hcol], pbf = bfv[hcol], pbo = bo[hcol], pbc = bc[hcol];
  float Creg = 0.f;

  // my production slice (wave 0): u64 index = batch*128 + 2w + half
  const int pslot = (lane >> 1) * 128 + 2 * w + (lane & 1);

  // B fragments -> registers (weights resident for the whole scan)
  short8 bfrag[8][2];
  {
    const int col0 = lane & 15;
    const int kqb  = (lane >> 4) * 8;
    #pragma unroll
    for (int ks = 0; ks < 8; ++ks) {
      int kb = (ks < 4) ? (wv * 128 + ks * 32 + kqb)
                        : (DH + wv * 128 + (ks - 4) * 32 + kqb);
      #pragma unroll
      for (int ni = 0; ni < 2; ++ni) {
        int col = ni * 16 + col0;
        bfrag[ks][ni] = *(const short8*)(Bws + ((size_t)(w * 32 + col) * KTOT + kb));
      }
    }
  }

  // pre-sentinel my slice of B_0, then one startup barrier (covers 0xAA poison)
  if (wv == 0) cstore(&hbuf64[pslot], SENT);

  // stage x_0 -> As[:, 512:1024)
  #pragma unroll
  for (int i = 0; i < 16; ++i) {
    int flat = tid + i * TPB;
    int row = flat >> 7, cc = flat & 127;
    float4 v = *(const float4*)(x + (size_t)row * (S_ * DIN) + cc * 4);
    uint2 p;
    p.x = (unsigned)f2bf(v.x) | ((unsigned)f2bf(v.y) << 16);
    p.y = (unsigned)f2bf(v.z) | ((unsigned)f2bf(v.w) << 16);
    *(uint2*)(&As[row * APAD + DIN + cc * 4]) = p;
  }

  // startup barrier: everyone's B_0 sentinels are at LLC before anyone proceeds
  if (tid == 0) {
    __builtin_amdgcn_s_waitcnt(0);
    __hip_atomic_fetch_add(&bar[(w & 7) * 32], 1u,
                           __ATOMIC_RELAXED, __HIP_MEMORY_SCOPE_AGENT);
    for (;;) {
      unsigned s = 0;
      #pragma unroll
      for (int i = 0; i < 8; ++i)
        s += __hip_atomic_load(&bar[i * 32], __ATOMIC_RELAXED, __HIP_MEMORY_SCOPE_AGENT);
      if (s >= (unsigned)NWG) break;
      __builtin_amdgcn_s_sleep(1);
    }
  }
  __syncthreads();

  const int r0 = lane & 15;
  const int kq = (lane >> 4) * 8;

  // x-part MFMA for t=0
  f32x4 acc00 = {0,0,0,0}, acc01 = {0,0,0,0}, acc10 = {0,0,0,0}, acc11 = {0,0,0,0};
  #pragma unroll
  for (int ks = 4; ks < 8; ++ks) {
    int koff = DH + wv * 128 + (ks - 4) * 32 + kq;
    short8 a0 = *(const short8*)(&As[r0 * APAD + koff]);
    short8 a1 = *(const short8*)(&As[(r0 + 16) * APAD + koff]);
    acc00 = mfma16(a0, bfrag[ks][0], acc00);
    acc01 = mfma16(a0, bfrag[ks][1], acc01);
    acc10 = mfma16(a1, bfrag[ks][0], acc10);
    acc11 = mfma16(a1, bfrag[ks][1], acc11);
  }

  for (int t = 0; t < S_; ++t) {
    if (t > 0) {
      // ---- sentinel-poll H_{t-1} from B_{(t-1)%3}: detect + load in one RTT ----
      const u64* hr = hbuf64 + (size_t)((t - 1) % 3) * HB64;
      u64 tmp[16];
      unsigned pending = 0xFFFFu;
      #pragma unroll
      for (int i = 0; i < 16; ++i) tmp[i] = cload(&hr[tid + i * TPB]);
      #pragma unroll
      for (int i = 0; i < 16; ++i) if (tmp[i] != SENT) pending &= ~(1u << i);
      while (pending) {
        #pragma unroll
        for (int i = 0; i < 16; ++i)
          if (pending & (1u << i)) tmp[i] = cload(&hr[tid + i * TPB]);
        #pragma unroll
        for (int i = 0; i < 16; ++i)
          if ((pending & (1u << i)) && tmp[i] != SENT) pending &= ~(1u << i);
      }
      #pragma unroll
      for (int i = 0; i < 16; ++i) {
        int flat = tid + i * TPB;
        int row = flat >> 7, cc = flat & 127;
        *(u64*)(&As[row * APAD + cc * 4]) = tmp[i];
      }
    }

    // re-sentinel my slice of B_{(t+1)%3} for use at step t+1 (safe: reaching here
    // implies all WGs finished polling H_{t-2} from that buffer)
    if (t + 1 < S_ && wv == 0)
      cstore(&hbuf64[(size_t)((t + 1) % 3) * HB64 + pslot], SENT);

    __syncthreads();

    if (t > 0) {
      // ---- H-part MFMA (accumulate onto x-part already in accs) ----
      #pragma unroll
      for (int ks = 0; ks < 4; ++ks) {
        int koff = wv * 128 + ks * 32 + kq;
        short8 a0 = *(const short8*)(&As[r0 * APAD + koff]);
        short8 a1 = *(const short8*)(&As[(r0 + 16) * APAD + koff]);
        acc00 = mfma16(a0, bfrag[ks][0], acc00);
        acc01 = mfma16(a0, bfrag[ks][1], acc01);
        acc10 = mfma16(a1, bfrag[ks][0], acc10);
        acc11 = mfma16(a1, bfrag[ks][1], acc11);
      }
    }

    {
      float* rp = &R[(wv * 64 + lane) * 16];
      *(f32x4*)(rp + 0)  = acc00;
      *(f32x4*)(rp + 4)  = acc01;
      *(f32x4*)(rp + 8)  = acc10;
      *(f32x4*)(rp + 12) = acc11;
    }
    __syncthreads();

    // ---- elementwise gate math ----
    float pre[4];
    {
      int r = eb & 15, mi = eb >> 4, reg = eb & 3;
      int lq = (r >> 2) * 16;
      #pragma unroll
      for (int g = 0; g < 4; ++g) {
        int c  = g * 8 + ej;
        int ni = c >> 4;
        int ln = (c & 15) + lq;
        int idx = (mi * 2 + ni) * 4 + reg;
        float s = 0.f;
        #pragma unroll
        for (int v = 0; v < 4; ++v) s += R[(v * 64 + ln) * 16 + idx];
        pre[g] = s;
      }
    }
    float I  = sigmoid_f(pre[0] + pbi);
    float F  = sigmoid_f(pre[1] + pbf);
    float O  = sigmoid_f(pre[2] + pbo);
    float Cc = tanh_f(pre[3] + pbc);
    Creg = F * Creg + I * Cc;
    float H = O * tanh_f(Creg);

    out[(size_t)eb * (S_ * DH) + (size_t)t * DH + hcol] = H;
    if (t == S_ - 1) out[(size_t)(B_ * S_ * DH) + eb * DH + hcol] = H;  // Hf
    Hs[tid] = f2bf(H);
    __syncthreads();

    if (t + 1 < S_) {
      // ---- publish H_t -> B_{t%3} (wave 0; waitcnt first so this iteration's
      // sentinel stores are at LLC before the data stores) ----
      if (tid < 64) {
        u64 v = (u64)Hs[tid * 4]
              | ((u64)Hs[tid * 4 + 1] << 16)
              | ((u64)Hs[tid * 4 + 2] << 32)
              | ((u64)Hs[tid * 4 + 3] << 48);
        if (tid == 0) __builtin_amdgcn_s_waitcnt(0);
        // all wave-0 lanes pass the same waitcnt point (wave-synchronous)
        cstore(&hbuf64[(size_t)(t % 3) * HB64 + pslot], v);
      }

      // ---- stage x_{t+1} + x-part MFMA (overlaps other WGs' latency) ----
      acc00 = (f32x4){0,0,0,0}; acc01 = (f32x4){0,0,0,0};
      acc10 = (f32x4){0,0,0,0}; acc11 = (f32x4){0,0,0,0};
      #pragma unroll
      for (int i = 0; i < 16; ++i) {
        int flat = tid + i * TPB;
        int row = flat >> 7, cc = flat & 127;
        float4 v = *(const float4*)(x + (size_t)row * (S_ * DIN) + (size_t)(t + 1) * DIN + cc * 4);
        uint2 p;
        p.x = (unsigned)f2bf(v.x) | ((unsigned)f2bf(v.y) << 16);
        p.y = (unsigned)f2bf(v.z) | ((unsigned)f2bf(v.w) << 16);
        *(uint2*)(&As[row * APAD + DIN + cc * 4]) = p;
      }
      __syncthreads();
      #pragma unroll
      for (int ks = 4; ks < 8; ++ks) {
        int koff = DH + wv * 128 + (ks - 4) * 32 + kq;
        short8 a0 = *(const short8*)(&As[r0 * APAD + koff]);
        short8 a1 = *(const short8*)(&As[(r0 + 16) * APAD + koff]);
        acc00 = mfma16(a0, bfrag[ks][0], acc00);
        acc01 = mfma16(a0, bfrag[ks][1], acc01);
        acc10 = mfma16(a1, bfrag[ks][0], acc10);
        acc11 = mfma16(a1, bfrag[ks][1], acc11);
      }
    }
  }
}

extern "C" void kernel_launch(void* const* d_in, const int* in_sizes, int n_in,
                              void* d_out, int out_size, void* d_ws, size_t ws_size,
                              hipStream_t stream) {
  const float* x   = (const float*)d_in[0];
  const float* Wxi = (const float*)d_in[1];
  const float* Whi = (const float*)d_in[2];
  const float* bi  = (const float*)d_in[3];
  const float* Wxf = (const float*)d_in[4];
  const float* Whf = (const float*)d_in[5];
  const float* bfv = (const float*)d_in[6];
  const float* Wxo = (const float*)d_in[7];
  const float* Who = (const float*)d_in[8];
  const float* bo  = (const float*)d_in[9];
  const float* Wxc = (const float*)d_in[10];
  const float* Whc = (const float*)d_in[11];
  const float* bc  = (const float*)d_in[12];
  float* out = (float*)d_out;

  // ws layout: Bws 4 MiB | hbuf 96 KiB (3 buffers) | bar 1 KiB
  unsigned short* Bws  = (unsigned short*)d_ws;
  u64*            hbuf = (u64*)((char*)d_ws + (size_t)4 * 1024 * 1024);
  unsigned*       bar  = (unsigned*)((char*)d_ws + (size_t)4 * 1024 * 1024 + 96 * 1024);

  k_prep<<<1024, TPB, 0, stream>>>(Whi, Whf, Who, Whc, Wxi, Wxf, Wxo, Wxc, Bws, bar);
  k_scan<<<NWG, TPB, 0, stream>>>(x, bi, bfv, bo, bc, Bws, hbuf, bar, out);
}